// Round 12
// baseline (90.942 us; speedup 1.0000x reference)
//
#include <hip/hip_runtime.h>

#define N_NODES 50000
#define N_EDGES 800000
#define C 64                          // channels (C_IN == C_HID == 64)
// edge binning: 256-dst-node buckets, counts-matrix (no global cursors/zeroing)
#define BUCKET_NODES 256
#define NBUCK 196                     // ceil(50000/256)
#define BIN_CHUNK 8192
#define NBIN 98                       // ceil(800000/8192)
#define CAP_CELL 128                  // per (chunk,bucket): mean 41.9, +13 sigma; pow2 -> no div
#define GRID_A 512
#define WPACK_BID 98
#define XCONV0 99
// fused filter+aggregate+mfma
#define AGG_NODES 16
#define NAGG (N_NODES / AGG_NODES)    // 3125 exactly (no tail)
#define NODE_CAP 64                   // max degree kept: Poisson(16), P(>=64)*50k ~ 1e-14
#define LDSTR 72                      // aggs row stride in shorts (144 B, 16B-aligned rows)

typedef __attribute__((ext_vector_type(8))) short bf16x8;
typedef __attribute__((ext_vector_type(4))) float f32x4;

__device__ inline unsigned short f2bf(float f) {          // round-to-nearest-even
    union { float f; unsigned u; } v; v.f = f;
    unsigned r = v.u + 0x7FFF + ((v.u >> 16) & 1);
    return (unsigned short)(r >> 16);
}
__device__ inline float bf2f(unsigned short h) {
    union { unsigned u; float f; } v; v.u = (unsigned)h << 16;
    return v.f;
}

// ---------------------------------------------------------------------------
// Kernel 1 (role-split by blockIdx):
//   [0..97]  : bin edges by dst>>8 into segmented bucketbuf[bucket][chunk][slot],
//              entry = (src<<8)|(dst&255). Per-block LDS counters only; the
//              counts MATRIX counts[chunk][bucket] replaces global cursors
//              (no global atomics, no zero-init dispatch; every cell count is
//              rewritten each call -> replay-deterministic).
//   [98]     : pack W,root into bf16 MFMA B-fragments (lane l holds
//              B[ks*32+(l>>4)*8+j][ct*16+(l&15)]).
//   [99..511]: convert x -> bf16 row-major (float4 in, ushort4 out).
// ---------------------------------------------------------------------------
__global__ __launch_bounds__(256) void prep_bin(
    const float* __restrict__ x,
    const int*   __restrict__ ei,
    const float* __restrict__ Wm,
    const float* __restrict__ Rm,
    unsigned short* __restrict__ xbf,
    uint4* __restrict__ wpack,
    int* __restrict__ counts,
    int* __restrict__ bucketbuf)
{
    const int bid = blockIdx.x;
    const int tid = threadIdx.x;

    if (bid < NBIN) {
        // ---- bin role ----
        __shared__ int sdst[BIN_CHUNK];               // 32 KB
        __shared__ int cnt[NBUCK], cnt2[NBUCK];
        for (int i = tid; i < NBUCK; i += 256) { cnt[i] = 0; cnt2[i] = 0; }
        __syncthreads();
        const int e0 = bid * BIN_CHUNK;
        const int ne = min(BIN_CHUNK, N_EDGES - e0);
        for (int k = tid; k < ne; k += 256) {
            const int d = ei[N_EDGES + e0 + k];
            sdst[k] = d;
            atomicAdd(&cnt[((unsigned)d) >> 8], 1);
        }
        __syncthreads();
        for (int j = tid; j < NBUCK; j += 256)
            counts[bid * NBUCK + j] = min(cnt[j], CAP_CELL);
        for (int k = tid; k < ne; k += 256) {
            const int src = ei[e0 + k];
            const int d   = sdst[k];
            const int j   = ((unsigned)d) >> 8;
            const int s   = atomicAdd(&cnt2[j], 1);
            if (s < CAP_CELL)
                bucketbuf[(((size_t)j * NBIN + bid) << 7) + s] =
                    (src << 8) | (d & 255);
        }
        return;
    }

    if (bid == WPACK_BID) {
        // ---- weight-pack role ----
        for (int s = tid; s < 1024; s += 256) {
            const int f = s >> 6;
            const int l = s & 63;
            const int mat = f >> 3, ks = (f >> 2) & 1, ct = f & 3;
            const float* srcm = mat ? Rm : Wm;
            const int kbase = ks * 32 + (l >> 4) * 8;
            const int col   = ct * 16 + (l & 15);
            unsigned wd[4];
            #pragma unroll
            for (int jj = 0; jj < 4; ++jj) {
                const unsigned lo16 = f2bf(srcm[(kbase + 2*jj    ) * C + col]);
                const unsigned hi16 = f2bf(srcm[(kbase + 2*jj + 1) * C + col]);
                wd[jj] = lo16 | (hi16 << 16);
            }
            uint4 o; o.x = wd[0]; o.y = wd[1]; o.z = wd[2]; o.w = wd[3];
            wpack[s] = o;
        }
        return;
    }

    // ---- x -> bf16 role (413 blocks) ----
    const int nthreads = (GRID_A - XCONV0) * 256;
    const int total4 = (N_NODES * C) / 4;             // 800000 float4
    for (int i = (bid - XCONV0) * 256 + tid; i < total4; i += nthreads) {
        const float4 v = ((const float4*)x)[i];
        ushort4 o;
        o.x = f2bf(v.x); o.y = f2bf(v.y); o.z = f2bf(v.z); o.w = f2bf(v.w);
        ((ushort4*)xbf)[i] = o;
    }
}

// ---------------------------------------------------------------------------
// Kernel 2 (fused filter + aggregate + MFMA). Block = 16 nodes (sub-tile
// `sub` of bucket `blockIdx/16`), 4 waves.
//  Filter: scan the bucket's 98 segmented cells (12544 slots, 49 iters,
//    pow2 indexing) and append entries whose (dst&255)>>4 == sub into LDS
//    per-node lists (degree falls out of the list counts). Replaces the
//    whole CSR stage; 16 blocks share an L2-hot 50 KB bucket region.
//  Gather: wave w owns nodes w*4..w*4+3; deg<=64 -> single chunk; 16-edge
//    steps with 4 independent uint2 loads in flight (lane-group g = edge
//    j+4u+g, lane r loads channels [4r,4r+4)); shfl_xor(16,32) reduce.
//  MFMA: out = relu(aggx@W + x@root + bias) — proven R8 epilogue.
// ---------------------------------------------------------------------------
__global__ __launch_bounds__(256) void agg_mfma(
    const int* __restrict__ counts,
    const int* __restrict__ bucketbuf,
    const unsigned short* __restrict__ xbf,
    const uint4*  __restrict__ wpack,
    const float*  __restrict__ bias,
    float* __restrict__ out)
{
    __shared__ int llist[AGG_NODES][NODE_CAP];        // 4 KB
    __shared__ int lcnt[AGG_NODES];
    __shared__ int cnts[NBIN];
    __shared__ unsigned short aggs[AGG_NODES][LDSTR]; // 2.3 KB

    const int tid  = threadIdx.x;
    const int lane = tid & 63;
    const int w    = tid >> 6;
    const int blk  = (int)blockIdx.x;
    const int bucket   = blk >> 4;
    const int sub      = blk & 15;
    const int tileBase = blk * AGG_NODES;

    if (tid < AGG_NODES) lcnt[tid] = 0;
    if (tid < NBIN)      cnts[tid] = counts[tid * NBUCK + bucket];
    __syncthreads();

    // ---- filter: bucket cells -> per-node LDS lists ----
    const int* mybuf = bucketbuf + ((size_t)bucket * NBIN << 7);
    for (int k = tid; k < (NBIN << 7); k += 256) {
        const int i = k >> 7;                         // chunk cell
        const int s = k & (CAP_CELL - 1);
        if (s < cnts[i]) {
            const int e   = mybuf[k];
            const int low = e & 255;
            if ((low >> 4) == sub) {
                const int nl  = low & 15;
                const int pos = atomicAdd(&lcnt[nl], 1);
                if (pos < NODE_CAP) llist[nl][pos] = e >> 8;
            }
        }
    }
    __syncthreads();

    const int r = lane & 15;      // channel-quad id: channels [4r, 4r+4)
    const int g = lane >> 4;      // edge-group id 0..3

    // ---- gather + mean (4 nodes per wave) ----
    #pragma unroll
    for (int i = 0; i < 4; ++i) {
        const int nl  = w * 4 + i;
        const int deg = min(lcnt[nl], NODE_CAP);
        const int sid = (lane < deg) ? llist[nl][lane] : 0;
        float a0 = 0.f, a1 = 0.f, a2 = 0.f, a3 = 0.f;
        int j = 0;
        for (; j + 16 <= deg; j += 16) {              // 4 gathers in flight
            const int s0 = __shfl(sid, j + g);
            const int s1 = __shfl(sid, j + 4  + g);
            const int s2 = __shfl(sid, j + 8  + g);
            const int s3 = __shfl(sid, j + 12 + g);
            const uint2 v0 = *(const uint2*)(xbf + (size_t)s0 * C + r * 4);
            const uint2 v1 = *(const uint2*)(xbf + (size_t)s1 * C + r * 4);
            const uint2 v2 = *(const uint2*)(xbf + (size_t)s2 * C + r * 4);
            const uint2 v3 = *(const uint2*)(xbf + (size_t)s3 * C + r * 4);
            a0 += bf2f((unsigned short)(v0.x & 0xffff)) +
                  bf2f((unsigned short)(v1.x & 0xffff)) +
                  bf2f((unsigned short)(v2.x & 0xffff)) +
                  bf2f((unsigned short)(v3.x & 0xffff));
            a1 += bf2f((unsigned short)(v0.x >> 16)) +
                  bf2f((unsigned short)(v1.x >> 16)) +
                  bf2f((unsigned short)(v2.x >> 16)) +
                  bf2f((unsigned short)(v3.x >> 16));
            a2 += bf2f((unsigned short)(v0.y & 0xffff)) +
                  bf2f((unsigned short)(v1.y & 0xffff)) +
                  bf2f((unsigned short)(v2.y & 0xffff)) +
                  bf2f((unsigned short)(v3.y & 0xffff));
            a3 += bf2f((unsigned short)(v0.y >> 16)) +
                  bf2f((unsigned short)(v1.y >> 16)) +
                  bf2f((unsigned short)(v2.y >> 16)) +
                  bf2f((unsigned short)(v3.y >> 16));
        }
        for (; j < deg; j += 4) {                     // tail (proven R7 form)
            const int  e     = j + g;
            const bool valid = e < deg;
            const int  s     = __shfl(sid, valid ? e : 0);
            const uint2 v = *(const uint2*)(xbf + (size_t)s * C + r * 4);
            if (valid) {
                a0 += bf2f((unsigned short)(v.x & 0xffff));
                a1 += bf2f((unsigned short)(v.x >> 16));
                a2 += bf2f((unsigned short)(v.y & 0xffff));
                a3 += bf2f((unsigned short)(v.y >> 16));
            }
        }
        #pragma unroll
        for (int off = 16; off <= 32; off <<= 1) {    // cross-group reduce
            a0 += __shfl_xor(a0, off);
            a1 += __shfl_xor(a1, off);
            a2 += __shfl_xor(a2, off);
            a3 += __shfl_xor(a3, off);
        }
        if (g == 0) {
            const float inv = 1.0f / fmaxf((float)deg, 1.0f);
            uint2 pv;
            pv.x = (unsigned)f2bf(a0 * inv) | ((unsigned)f2bf(a1 * inv) << 16);
            pv.y = (unsigned)f2bf(a2 * inv) | ((unsigned)f2bf(a3 * inv) << 16);
            *(uint2*)&aggs[w * 4 + i][r * 4] = pv;
        }
    }
    __syncthreads();

    // ---- MFMA epilogue (wave w = channel tile w; R8-proven) ----
    const int q = lane >> 4;

    const bf16x8 bw0 = *(const bf16x8*)&wpack[(0*8 + 0*4 + w) * 64 + lane];
    const bf16x8 bw1 = *(const bf16x8*)&wpack[(0*8 + 1*4 + w) * 64 + lane];
    const bf16x8 br0 = *(const bf16x8*)&wpack[(1*8 + 0*4 + w) * 64 + lane];
    const bf16x8 br1 = *(const bf16x8*)&wpack[(1*8 + 1*4 + w) * 64 + lane];
    const float  bb  = bias[w * 16 + r];

    const unsigned short* rx = xbf + (size_t)(tileBase + r) * C;
    const bf16x8 a0 = *(const bf16x8*)&aggs[r][q * 8];
    const bf16x8 a1 = *(const bf16x8*)&aggs[r][32 + q * 8];
    const bf16x8 a2 = *(const bf16x8*)(rx + q * 8);
    const bf16x8 a3 = *(const bf16x8*)(rx + 32 + q * 8);

    f32x4 acc4 = {0.f, 0.f, 0.f, 0.f};
    acc4 = __builtin_amdgcn_mfma_f32_16x16x32_bf16(a0, bw0, acc4, 0, 0, 0);
    acc4 = __builtin_amdgcn_mfma_f32_16x16x32_bf16(a1, bw1, acc4, 0, 0, 0);
    acc4 = __builtin_amdgcn_mfma_f32_16x16x32_bf16(a2, br0, acc4, 0, 0, 0);
    acc4 = __builtin_amdgcn_mfma_f32_16x16x32_bf16(a3, br1, acc4, 0, 0, 0);

    #pragma unroll
    for (int i = 0; i < 4; ++i) {
        const int node = tileBase + q * 4 + i;
        out[(size_t)node * C + w * 16 + r] = fmaxf(acc4[i] + bb, 0.f);
    }
}

// ---------------------------------------------------------------------------
// Launch (2 dispatches, no zero-init). ws layout (16B-aligned):
//   xbf       : ushort[3,200,000]            6.4  MB
//   wpack     : uint4[1024]                  16   KB
//   counts    : int[19456] (98*196 used)     78   KB
//   bucketbuf : int[196*98*128]              9.8  MB    total ~16.3 MB
// ---------------------------------------------------------------------------
extern "C" void kernel_launch(void* const* d_in, const int* in_sizes, int n_in,
                              void* d_out, int out_size, void* d_ws, size_t ws_size,
                              hipStream_t stream)
{
    const float* x    = (const float*)d_in[0];
    const int*   ei   = (const int*)d_in[1];
    // d_in[2] = edge_attr: drops out for kernel_size=1 SplineConv
    const float* W    = (const float*)d_in[3];
    const float* R    = (const float*)d_in[4];
    const float* bias = (const float*)d_in[5];

    char* wsb = (char*)d_ws;
    unsigned short* xbf = (unsigned short*)wsb;
    size_t off = (size_t)N_NODES * C * sizeof(unsigned short);
    uint4* wpack     = (uint4*)(wsb + off);  off += 1024 * sizeof(uint4);
    int*   counts    = (int*)(wsb + off);    off += 19456 * sizeof(int);
    int*   bucketbuf = (int*)(wsb + off);
    float* out       = (float*)d_out;

    prep_bin<<<GRID_A, 256, 0, stream>>>(x, ei, W, R, xbf, wpack,
                                         counts, bucketbuf);
    agg_mfma<<<NAGG, 256, 0, stream>>>(counts, bucketbuf, xbf, wpack, bias, out);
}

// Round 13
// 67.980 us; speedup vs baseline: 1.3378x; 1.3378x over previous
//
#include <hip/hip_runtime.h>

#define N_NODES 50000
#define N_EDGES 800000
#define C 64                          // channels (C_IN == C_HID == 64)
// edge binning
#define BUCKET_NODES 256
#define NBUCK 196                     // ceil(50000/256)
#define BUCKET_CAP 6144               // mean 4082, +32 sigma (proven on this graph)
#define BIN_CHUNK 8192
#define NBIN_BLOCKS 98                // ceil(800000/8192)
#define PREP_XBLOCKS 199
#define PB_BLOCKS (1 + PREP_XBLOCKS + NBIN_BLOCKS)           // 298
// fused aggregate+mfma
#define AGG_NODES 16
#define NAGG (N_NODES / AGG_NODES)    // 3125 exactly (no tail)
#define LDSTR 72                      // LDS row stride in shorts (144 B, 16B-aligned rows)

typedef __attribute__((ext_vector_type(8))) short bf16x8;
typedef __attribute__((ext_vector_type(4))) float f32x4;

__device__ inline unsigned short f2bf(float f) {          // round-to-nearest-even
    union { float f; unsigned u; } v; v.f = f;
    unsigned r = v.u + 0x7FFF + ((v.u >> 16) & 1);
    return (unsigned short)(r >> 16);
}
__device__ inline float bf2f(unsigned short h) {
    union { unsigned u; float f; } v; v.u = (unsigned)h << 16;
    return v.f;
}

// ---------------------------------------------------------------------------
// Kernel 0: zero the 256-int bucket cursor (cheap dispatch, graph-friendly).
// ---------------------------------------------------------------------------
__global__ __launch_bounds__(256) void zero_cursor(int* __restrict__ c)
{
    c[threadIdx.x] = 0;
}

// ---------------------------------------------------------------------------
// Kernel 1 (fused, role-split by blockIdx) — R8-proven:
//   block 0            : pack W,root into bf16 MFMA B-fragments
//   blocks 1..199      : convert x -> bf16 row-major
//   blocks 200..297    : bin edges by dst>>8 (entry = (src<<8)|(dst&255))
// B-frag layout for mfma_f32_16x16x32_bf16: lane l holds
//   B[k = ks*32 + (l>>4)*8 + j][col = ct*16 + (l&15)], j=0..7.
// wpack slot s = f*64 + lane, f = mat*8 + ks*4 + ct  (mat 0=W, 1=root).
// ---------------------------------------------------------------------------
__global__ __launch_bounds__(256) void prep_bin(
    const float* __restrict__ x,
    const float* __restrict__ W,
    const float* __restrict__ R,
    const int*   __restrict__ ei,
    unsigned short* __restrict__ xbf,
    uint4* __restrict__ wpack,
    int* __restrict__ bucketCursor,
    int* __restrict__ bucketbuf)
{
    const int bid = blockIdx.x;

    if (bid == 0) {
        // ---- weight-pack role ----
        for (int s = threadIdx.x; s < 1024; s += 256) {
            const int f    = s >> 6;
            const int lane = s & 63;
            const int mat  = f >> 3, ks = (f >> 2) & 1, ct = f & 3;
            const float* src = mat ? R : W;
            const int kbase = ks * 32 + (lane >> 4) * 8;
            const int col   = ct * 16 + (lane & 15);
            unsigned wd[4];
            #pragma unroll
            for (int jj = 0; jj < 4; ++jj) {
                const unsigned lo16 = f2bf(src[(kbase + 2*jj    ) * C + col]);
                const unsigned hi16 = f2bf(src[(kbase + 2*jj + 1) * C + col]);
                wd[jj] = lo16 | (hi16 << 16);
            }
            uint4 o; o.x = wd[0]; o.y = wd[1]; o.z = wd[2]; o.w = wd[3];
            wpack[s] = o;
        }
        return;
    }

    if (bid <= PREP_XBLOCKS) {
        // ---- x-convert role ----
        const int nthreads = PREP_XBLOCKS * 256;
        const int total4 = (N_NODES * C) / 4;             // 800000 float4
        for (int i = (bid - 1) * 256 + threadIdx.x; i < total4; i += nthreads) {
            const float4 v = ((const float4*)x)[i];
            ushort4 o;
            o.x = f2bf(v.x); o.y = f2bf(v.y); o.z = f2bf(v.z); o.w = f2bf(v.w);
            ((ushort4*)xbf)[i] = o;
        }
        return;
    }

    // ---- edge-bin role (dst staged in LDS to avoid HBM re-read) ----
    __shared__ int sdst[BIN_CHUNK];                       // 32 KB
    __shared__ int cnt[NBUCK], cnt2[NBUCK], gb[NBUCK];
    for (int i = threadIdx.x; i < NBUCK; i += 256) { cnt[i] = 0; cnt2[i] = 0; }
    __syncthreads();

    const int bb = bid - 1 - PREP_XBLOCKS;
    const int e0 = bb * BIN_CHUNK;
    const int e1 = min(e0 + BIN_CHUNK, N_EDGES);
    const int ne = e1 - e0;

    for (int k = threadIdx.x; k < ne; k += 256) {
        const int d = ei[N_EDGES + e0 + k];
        sdst[k] = d;
        atomicAdd(&cnt[((unsigned)d) >> 8], 1);
    }
    __syncthreads();

    for (int i = threadIdx.x; i < NBUCK; i += 256)
        gb[i] = atomicAdd(&bucketCursor[i], cnt[i]);
    __syncthreads();

    for (int k = threadIdx.x; k < ne; k += 256) {
        const int src = ei[e0 + k];
        const int dst = sdst[k];
        const int bkt = ((unsigned)dst) >> 8;
        const int off = gb[bkt] + atomicAdd(&cnt2[bkt], 1);
        bucketbuf[bkt * BUCKET_CAP + off] = (src << 8) | (dst & 255);
    }
}

// ---------------------------------------------------------------------------
// Kernel 2: per-bucket {stage entries, LDS degree-hist, block scan, rowptr
// write, CSR placement} — all fused (R8-proven). Bucket offset derived
// in-block by wave 0 scanning bucketCursor (196 ints, L2-hot).
// ---------------------------------------------------------------------------
__global__ __launch_bounds__(256) void csr_place_scan(
    const int* __restrict__ bucketCursor,
    const int* __restrict__ bucketbuf,
    int* __restrict__ rowptr,
    int* __restrict__ ebuf)
{
    __shared__ int entries[BUCKET_CAP];                   // 24 KB
    __shared__ int lcur[BUCKET_NODES];
    __shared__ int wsum[4];
    __shared__ int boffS;

    const int b    = blockIdx.x;
    const int tid  = threadIdx.x;
    const int lane = tid & 63, w = tid >> 6;
    const int lo   = b * BUCKET_NODES;
    const int nn   = min(BUCKET_NODES, N_NODES - lo);
    const int cnt  = bucketCursor[b];

    if (w == 0) {                                         // bucket-offset scan
        const int base = lane * 4;
        int s0 = (base+0 < NBUCK) ? bucketCursor[base+0] : 0;
        int s1 = (base+1 < NBUCK) ? bucketCursor[base+1] : 0;
        int s2 = (base+2 < NBUCK) ? bucketCursor[base+2] : 0;
        int s3 = (base+3 < NBUCK) ? bucketCursor[base+3] : 0;
        const int tot = s0 + s1 + s2 + s3;
        int incl = tot;
        #pragma unroll
        for (int off = 1; off < 64; off <<= 1) {
            const int t = __shfl_up(incl, off);
            if (lane >= off) incl += t;
        }
        if (lane == (b >> 2)) {
            int v = incl - tot;
            if ((b & 3) > 0) v += s0;
            if ((b & 3) > 1) v += s1;
            if ((b & 3) > 2) v += s2;
            boffS = v;
        }
    }

    lcur[tid] = 0;
    for (int k = tid; k < cnt; k += 256) entries[k] = bucketbuf[b * BUCKET_CAP + k];
    __syncthreads();

    for (int k = tid; k < cnt; k += 256)
        atomicAdd(&lcur[entries[k] & 255], 1);            // LDS degree hist
    __syncthreads();

    const int v = (tid < nn) ? lcur[tid] : 0;
    int incl = v;                                         // block exclusive scan
    #pragma unroll
    for (int off = 1; off < 64; off <<= 1) {
        const int t = __shfl_up(incl, off);
        if (lane >= off) incl += t;
    }
    if (lane == 63) wsum[w] = incl;
    __syncthreads();
    int woff = boffS;
    for (int k2 = 0; k2 < 4; ++k2) if (k2 < w) woff += wsum[k2];
    const int excl = woff + incl - v;
    __syncthreads();                                      // all v-reads done
    if (tid < nn) {
        rowptr[lo + tid] = excl;
        lcur[tid] = excl;
        if (lo + tid == N_NODES - 1) rowptr[N_NODES] = excl + v;
    }
    __syncthreads();

    for (int k = tid; k < cnt; k += 256) {                // placement
        const int p   = entries[k];
        const int pos = atomicAdd(&lcur[p & 255], 1);
        ebuf[pos] = p >> 8;
    }
}

// ---------------------------------------------------------------------------
// Kernel 3 (fused): aggregate x (mean over incoming edges) into an LDS tile,
// then MFMA epilogue: out = relu( aggx @ W + x @ root + bias ).
// Block = 16 nodes, 4 waves (R8-proven structure). ONLY delta vs R8:
// 16-edge gather steps with 4 INDEPENDENT uint2 loads in flight before any
// accumulate (gather shown latency-bound at max occupancy; MLP 1 -> 4).
// ---------------------------------------------------------------------------
__global__ __launch_bounds__(256) void agg_mfma(
    const int* __restrict__ rowptr,
    const int* __restrict__ ebuf,
    const unsigned short* __restrict__ xbf,
    const uint4*  __restrict__ wpack,
    const float*  __restrict__ bias,
    float* __restrict__ out)
{
    __shared__ unsigned short aggs[AGG_NODES][LDSTR];

    const int lane = threadIdx.x & 63;
    const int w    = threadIdx.x >> 6;
    const int tileBase = (int)blockIdx.x * AGG_NODES;

    const int r = lane & 15;      // channel-quad id: channels [4r, 4r+4)
    const int g = lane >> 4;      // edge-group id 0..3

    // ---- phase 1: aggregation (4 nodes per wave) ----
    #pragma unroll
    for (int i = 0; i < 4; ++i) {
        const int n   = tileBase + w * 4 + i;
        const int beg = rowptr[n];
        const int end = rowptr[n + 1];
        float a0 = 0.f, a1 = 0.f, a2 = 0.f, a3 = 0.f;
        for (int base = beg; base < end; base += 64) {
            const int m = min(64, end - base);
            const int sid = (base + lane < end) ? ebuf[base + lane] : 0;
            int j = 0;
            for (; j + 16 <= m; j += 16) {            // 4 gathers in flight
                const int s0 = __shfl(sid, j + g);
                const int s1 = __shfl(sid, j + 4  + g);
                const int s2 = __shfl(sid, j + 8  + g);
                const int s3 = __shfl(sid, j + 12 + g);
                const uint2 v0 = *(const uint2*)(xbf + (size_t)s0 * C + r * 4);
                const uint2 v1 = *(const uint2*)(xbf + (size_t)s1 * C + r * 4);
                const uint2 v2 = *(const uint2*)(xbf + (size_t)s2 * C + r * 4);
                const uint2 v3 = *(const uint2*)(xbf + (size_t)s3 * C + r * 4);
                a0 += bf2f((unsigned short)(v0.x & 0xffff)) +
                      bf2f((unsigned short)(v1.x & 0xffff)) +
                      bf2f((unsigned short)(v2.x & 0xffff)) +
                      bf2f((unsigned short)(v3.x & 0xffff));
                a1 += bf2f((unsigned short)(v0.x >> 16)) +
                      bf2f((unsigned short)(v1.x >> 16)) +
                      bf2f((unsigned short)(v2.x >> 16)) +
                      bf2f((unsigned short)(v3.x >> 16));
                a2 += bf2f((unsigned short)(v0.y & 0xffff)) +
                      bf2f((unsigned short)(v1.y & 0xffff)) +
                      bf2f((unsigned short)(v2.y & 0xffff)) +
                      bf2f((unsigned short)(v3.y & 0xffff));
                a3 += bf2f((unsigned short)(v0.y >> 16)) +
                      bf2f((unsigned short)(v1.y >> 16)) +
                      bf2f((unsigned short)(v2.y >> 16)) +
                      bf2f((unsigned short)(v3.y >> 16));
            }
            for (; j < m; j += 4) {                   // tail (proven R7 form)
                const int  e     = j + g;
                const bool valid = e < m;
                const int  s     = __shfl(sid, valid ? e : 0);
                const uint2 v = *(const uint2*)(xbf + (size_t)s * C + r * 4);
                if (valid) {
                    a0 += bf2f((unsigned short)(v.x & 0xffff));
                    a1 += bf2f((unsigned short)(v.x >> 16));
                    a2 += bf2f((unsigned short)(v.y & 0xffff));
                    a3 += bf2f((unsigned short)(v.y >> 16));
                }
            }
        }
        #pragma unroll
        for (int off = 16; off <= 32; off <<= 1) {    // cross-group reduce
            a0 += __shfl_xor(a0, off);
            a1 += __shfl_xor(a1, off);
            a2 += __shfl_xor(a2, off);
            a3 += __shfl_xor(a3, off);
        }
        if (g == 0) {
            const float inv = 1.0f / fmaxf((float)(end - beg), 1.0f);
            uint2 pv;
            pv.x = (unsigned)f2bf(a0 * inv) | ((unsigned)f2bf(a1 * inv) << 16);
            pv.y = (unsigned)f2bf(a2 * inv) | ((unsigned)f2bf(a3 * inv) << 16);
            *(uint2*)&aggs[w * 4 + i][r * 4] = pv;
        }
    }
    __syncthreads();

    // ---- phase 2: MFMA epilogue (wave w = channel tile w; R8-proven) ----
    const int q = lane >> 4;

    const bf16x8 bw0 = *(const bf16x8*)&wpack[(0*8 + 0*4 + w) * 64 + lane];
    const bf16x8 bw1 = *(const bf16x8*)&wpack[(0*8 + 1*4 + w) * 64 + lane];
    const bf16x8 br0 = *(const bf16x8*)&wpack[(1*8 + 0*4 + w) * 64 + lane];
    const bf16x8 br1 = *(const bf16x8*)&wpack[(1*8 + 1*4 + w) * 64 + lane];
    const float  bb  = bias[w * 16 + r];

    const unsigned short* rx = xbf + (size_t)(tileBase + r) * C;
    const bf16x8 a0 = *(const bf16x8*)&aggs[r][q * 8];
    const bf16x8 a1 = *(const bf16x8*)&aggs[r][32 + q * 8];
    const bf16x8 a2 = *(const bf16x8*)(rx + q * 8);
    const bf16x8 a3 = *(const bf16x8*)(rx + 32 + q * 8);

    f32x4 acc4 = {0.f, 0.f, 0.f, 0.f};
    acc4 = __builtin_amdgcn_mfma_f32_16x16x32_bf16(a0, bw0, acc4, 0, 0, 0);
    acc4 = __builtin_amdgcn_mfma_f32_16x16x32_bf16(a1, bw1, acc4, 0, 0, 0);
    acc4 = __builtin_amdgcn_mfma_f32_16x16x32_bf16(a2, br0, acc4, 0, 0, 0);
    acc4 = __builtin_amdgcn_mfma_f32_16x16x32_bf16(a3, br1, acc4, 0, 0, 0);

    #pragma unroll
    for (int i = 0; i < 4; ++i) {
        const int node = tileBase + q * 4 + i;
        out[(size_t)node * C + w * 16 + r] = fmaxf(acc4[i] + bb, 0.f);
    }
}

// ---------------------------------------------------------------------------
// Launch (R8-proven 4-dispatch pipeline). ws layout (16B-aligned):
//   xbf          : ushort[3,200,000]   6.4 MB
//   wpack        : uint4[1024]         16 KB
//   bucketCursor : int[256]            (zeroed by kernel 0)
//   rowptr       : int[50,008]
//   ebuf         : int[800,000]        3.2 MB
//   bucketbuf    : int[196*6144]       4.8 MB     total ~14.7 MB
// ---------------------------------------------------------------------------
extern "C" void kernel_launch(void* const* d_in, const int* in_sizes, int n_in,
                              void* d_out, int out_size, void* d_ws, size_t ws_size,
                              hipStream_t stream)
{
    const float* x    = (const float*)d_in[0];
    const int*   ei   = (const int*)d_in[1];
    // d_in[2] = edge_attr: drops out for kernel_size=1 SplineConv
    const float* W    = (const float*)d_in[3];
    const float* R    = (const float*)d_in[4];
    const float* bias = (const float*)d_in[5];

    char* wsb = (char*)d_ws;
    unsigned short* xbf = (unsigned short*)wsb;
    size_t off = (size_t)N_NODES * C * sizeof(unsigned short);
    uint4* wpack        = (uint4*)(wsb + off);  off += 1024 * sizeof(uint4);
    int*   bucketCursor = (int*)(wsb + off);    off += 256 * sizeof(int);
    int*   rowptr       = (int*)(wsb + off);    off += ((N_NODES + 8) & ~3) * sizeof(int);
    int*   ebuf         = (int*)(wsb + off);    off += (size_t)N_EDGES * sizeof(int);
    int*   bucketbuf    = (int*)(wsb + off);
    float* out          = (float*)d_out;

    zero_cursor   <<<1, 256, 0, stream>>>(bucketCursor);
    prep_bin      <<<PB_BLOCKS, 256, 0, stream>>>(x, W, R, ei, xbf, wpack,
                                                  bucketCursor, bucketbuf);
    csr_place_scan<<<NBUCK, 256, 0, stream>>>(bucketCursor, bucketbuf, rowptr, ebuf);
    agg_mfma      <<<NAGG, 256, 0, stream>>>(rowptr, ebuf, xbf, wpack, bias, out);
}

// Round 14
// 59.943 us; speedup vs baseline: 1.5171x; 1.1341x over previous
//
#include <hip/hip_runtime.h>

#define N_NODES 50000
#define N_EDGES 800000
#define C 64                          // channels (C_IN == C_HID == 64)
// edge binning
#define BUCKET_NODES 256
#define NBUCK 196                     // ceil(50000/256)
#define BUCKET_CAP 6144               // mean 4082, +32 sigma (proven on this graph)
#define BIN_CHUNK 4096
#define NBIN_BLOCKS 196               // 196*4096 >= 800000
#define PREP_XBLOCKS 315
#define PB_BLOCKS (1 + PREP_XBLOCKS + NBIN_BLOCKS)           // 512 = 2 blocks/CU
#define BIN0 (1 + PREP_XBLOCKS)       // first bin block
// fused aggregate+mfma
#define AGG_NODES 16
#define NAGG (N_NODES / AGG_NODES)    // 3125 exactly (no tail)
#define LDSTR 72                      // LDS row stride in shorts (144 B, 16B-aligned rows)

typedef __attribute__((ext_vector_type(8))) short bf16x8;
typedef __attribute__((ext_vector_type(4))) float f32x4;

__device__ inline unsigned short f2bf(float f) {          // round-to-nearest-even
    union { float f; unsigned u; } v; v.f = f;
    unsigned r = v.u + 0x7FFF + ((v.u >> 16) & 1);
    return (unsigned short)(r >> 16);
}
__device__ inline float bf2f(unsigned short h) {
    union { unsigned u; float f; } v; v.u = (unsigned)h << 16;
    return v.f;
}

// ---------------------------------------------------------------------------
// Kernel 0: zero the 256-int bucket cursor (cheap dispatch, graph-friendly).
// ---------------------------------------------------------------------------
__global__ __launch_bounds__(256) void zero_cursor(int* __restrict__ c)
{
    c[threadIdx.x] = 0;
}

// ---------------------------------------------------------------------------
// Kernel 1 (fused, role-split by blockIdx) — R8-proven body, rebalanced grid:
//   block 0            : pack W,root into bf16 MFMA B-fragments
//   blocks 1..315      : convert x -> bf16 row-major
//   blocks 316..511    : bin edges by dst>>8 (entry = (src<<8)|(dst&255)),
//                        4096-edge chunks (half the LDS-atomic contention,
//                        2x block overlap vs R13's 8192).
// ---------------------------------------------------------------------------
__global__ __launch_bounds__(256) void prep_bin(
    const float* __restrict__ x,
    const float* __restrict__ W,
    const float* __restrict__ R,
    const int*   __restrict__ ei,
    unsigned short* __restrict__ xbf,
    uint4* __restrict__ wpack,
    int* __restrict__ bucketCursor,
    int* __restrict__ bucketbuf)
{
    const int bid = blockIdx.x;

    if (bid == 0) {
        // ---- weight-pack role ----
        for (int s = threadIdx.x; s < 1024; s += 256) {
            const int f    = s >> 6;
            const int lane = s & 63;
            const int mat  = f >> 3, ks = (f >> 2) & 1, ct = f & 3;
            const float* src = mat ? R : W;
            const int kbase = ks * 32 + (lane >> 4) * 8;
            const int col   = ct * 16 + (lane & 15);
            unsigned wd[4];
            #pragma unroll
            for (int jj = 0; jj < 4; ++jj) {
                const unsigned lo16 = f2bf(src[(kbase + 2*jj    ) * C + col]);
                const unsigned hi16 = f2bf(src[(kbase + 2*jj + 1) * C + col]);
                wd[jj] = lo16 | (hi16 << 16);
            }
            uint4 o; o.x = wd[0]; o.y = wd[1]; o.z = wd[2]; o.w = wd[3];
            wpack[s] = o;
        }
        return;
    }

    if (bid < BIN0) {
        // ---- x-convert role (315 blocks) ----
        const int nthreads = PREP_XBLOCKS * 256;
        const int total4 = (N_NODES * C) / 4;             // 800000 float4
        for (int i = (bid - 1) * 256 + threadIdx.x; i < total4; i += nthreads) {
            const float4 v = ((const float4*)x)[i];
            ushort4 o;
            o.x = f2bf(v.x); o.y = f2bf(v.y); o.z = f2bf(v.z); o.w = f2bf(v.w);
            ((ushort4*)xbf)[i] = o;
        }
        return;
    }

    // ---- edge-bin role (196 blocks; dst staged in LDS) ----
    __shared__ int sdst[BIN_CHUNK];                       // 16 KB
    __shared__ int cnt[NBUCK], cnt2[NBUCK], gb[NBUCK];
    for (int i = threadIdx.x; i < NBUCK; i += 256) { cnt[i] = 0; cnt2[i] = 0; }
    __syncthreads();

    const int bb = bid - BIN0;
    const int e0 = bb * BIN_CHUNK;
    const int e1 = min(e0 + BIN_CHUNK, N_EDGES);
    const int ne = e1 - e0;

    for (int k = threadIdx.x; k < ne; k += 256) {
        const int d = ei[N_EDGES + e0 + k];
        sdst[k] = d;
        atomicAdd(&cnt[((unsigned)d) >> 8], 1);
    }
    __syncthreads();

    for (int i = threadIdx.x; i < NBUCK; i += 256)
        gb[i] = atomicAdd(&bucketCursor[i], cnt[i]);
    __syncthreads();

    for (int k = threadIdx.x; k < ne; k += 256) {
        const int src = ei[e0 + k];
        const int dst = sdst[k];
        const int bkt = ((unsigned)dst) >> 8;
        const int off = gb[bkt] + atomicAdd(&cnt2[bkt], 1);
        bucketbuf[bkt * BUCKET_CAP + off] = (src << 8) | (dst & 255);
    }
}

// ---------------------------------------------------------------------------
// Kernel 2: per-bucket {stage entries, LDS degree-hist, block scan, rowptr
// write, CSR placement} — R8-proven logic, widened to 512 threads (8 waves):
// staging/hist/placement loops halve in trip count; the 256-node scan phase
// runs in waves 0..3 (all barriers block-uniform).
// ---------------------------------------------------------------------------
__global__ __launch_bounds__(512) void csr_place_scan(
    const int* __restrict__ bucketCursor,
    const int* __restrict__ bucketbuf,
    int* __restrict__ rowptr,
    int* __restrict__ ebuf)
{
    __shared__ int entries[BUCKET_CAP];                   // 24 KB
    __shared__ int lcur[BUCKET_NODES];
    __shared__ int wsum[4];
    __shared__ int boffS;

    const int b    = blockIdx.x;
    const int tid  = threadIdx.x;
    const int lane = tid & 63, w = tid >> 6;
    const int lo   = b * BUCKET_NODES;
    const int nn   = min(BUCKET_NODES, N_NODES - lo);
    const int cnt  = bucketCursor[b];

    if (w == 0) {                                         // bucket-offset scan
        const int base = lane * 4;
        int s0 = (base+0 < NBUCK) ? bucketCursor[base+0] : 0;
        int s1 = (base+1 < NBUCK) ? bucketCursor[base+1] : 0;
        int s2 = (base+2 < NBUCK) ? bucketCursor[base+2] : 0;
        int s3 = (base+3 < NBUCK) ? bucketCursor[base+3] : 0;
        const int tot = s0 + s1 + s2 + s3;
        int incl = tot;
        #pragma unroll
        for (int off = 1; off < 64; off <<= 1) {
            const int t = __shfl_up(incl, off);
            if (lane >= off) incl += t;
        }
        if (lane == (b >> 2)) {
            int v = incl - tot;
            if ((b & 3) > 0) v += s0;
            if ((b & 3) > 1) v += s1;
            if ((b & 3) > 2) v += s2;
            boffS = v;
        }
    }

    if (tid < BUCKET_NODES) lcur[tid] = 0;
    for (int k = tid; k < cnt; k += 512) entries[k] = bucketbuf[b * BUCKET_CAP + k];
    __syncthreads();

    for (int k = tid; k < cnt; k += 512)
        atomicAdd(&lcur[entries[k] & 255], 1);            // LDS degree hist
    __syncthreads();

    int v = 0, incl = 0;
    if (tid < BUCKET_NODES) {                             // block exclusive scan
        v = (tid < nn) ? lcur[tid] : 0;
        incl = v;
        #pragma unroll
        for (int off = 1; off < 64; off <<= 1) {
            const int t = __shfl_up(incl, off);
            if (lane >= off) incl += t;
        }
        if (lane == 63) wsum[w] = incl;
    }
    __syncthreads();
    int excl = 0;
    if (tid < BUCKET_NODES) {
        int woff = boffS;
        for (int k2 = 0; k2 < 4; ++k2) if (k2 < w) woff += wsum[k2];
        excl = woff + incl - v;
    }
    __syncthreads();                                      // all v-reads done
    if (tid < nn) {
        rowptr[lo + tid] = excl;
        lcur[tid] = excl;
        if (lo + tid == N_NODES - 1) rowptr[N_NODES] = excl + v;
    }
    __syncthreads();

    for (int k = tid; k < cnt; k += 512) {                // placement
        const int p   = entries[k];
        const int pos = atomicAdd(&lcur[p & 255], 1);
        ebuf[pos] = p >> 8;
    }
}

// ---------------------------------------------------------------------------
// Kernel 3 (fused): aggregate x (mean over incoming edges) into an LDS tile,
// then MFMA epilogue: out = relu( aggx @ W + x @ root + bias ).
// R13-proven: block = 16 nodes, 4 waves; 16-edge gather steps with 4
// independent uint2 loads in flight; shfl_xor(16,32) cross-group reduce.
// ---------------------------------------------------------------------------
__global__ __launch_bounds__(256) void agg_mfma(
    const int* __restrict__ rowptr,
    const int* __restrict__ ebuf,
    const unsigned short* __restrict__ xbf,
    const uint4*  __restrict__ wpack,
    const float*  __restrict__ bias,
    float* __restrict__ out)
{
    __shared__ unsigned short aggs[AGG_NODES][LDSTR];

    const int lane = threadIdx.x & 63;
    const int w    = threadIdx.x >> 6;
    const int tileBase = (int)blockIdx.x * AGG_NODES;

    const int r = lane & 15;      // channel-quad id: channels [4r, 4r+4)
    const int g = lane >> 4;      // edge-group id 0..3

    // ---- phase 1: aggregation (4 nodes per wave) ----
    #pragma unroll
    for (int i = 0; i < 4; ++i) {
        const int n   = tileBase + w * 4 + i;
        const int beg = rowptr[n];
        const int end = rowptr[n + 1];
        float a0 = 0.f, a1 = 0.f, a2 = 0.f, a3 = 0.f;
        for (int base = beg; base < end; base += 64) {
            const int m = min(64, end - base);
            const int sid = (base + lane < end) ? ebuf[base + lane] : 0;
            int j = 0;
            for (; j + 16 <= m; j += 16) {            // 4 gathers in flight
                const int s0 = __shfl(sid, j + g);
                const int s1 = __shfl(sid, j + 4  + g);
                const int s2 = __shfl(sid, j + 8  + g);
                const int s3 = __shfl(sid, j + 12 + g);
                const uint2 v0 = *(const uint2*)(xbf + (size_t)s0 * C + r * 4);
                const uint2 v1 = *(const uint2*)(xbf + (size_t)s1 * C + r * 4);
                const uint2 v2 = *(const uint2*)(xbf + (size_t)s2 * C + r * 4);
                const uint2 v3 = *(const uint2*)(xbf + (size_t)s3 * C + r * 4);
                a0 += bf2f((unsigned short)(v0.x & 0xffff)) +
                      bf2f((unsigned short)(v1.x & 0xffff)) +
                      bf2f((unsigned short)(v2.x & 0xffff)) +
                      bf2f((unsigned short)(v3.x & 0xffff));
                a1 += bf2f((unsigned short)(v0.x >> 16)) +
                      bf2f((unsigned short)(v1.x >> 16)) +
                      bf2f((unsigned short)(v2.x >> 16)) +
                      bf2f((unsigned short)(v3.x >> 16));
                a2 += bf2f((unsigned short)(v0.y & 0xffff)) +
                      bf2f((unsigned short)(v1.y & 0xffff)) +
                      bf2f((unsigned short)(v2.y & 0xffff)) +
                      bf2f((unsigned short)(v3.y & 0xffff));
                a3 += bf2f((unsigned short)(v0.y >> 16)) +
                      bf2f((unsigned short)(v1.y >> 16)) +
                      bf2f((unsigned short)(v2.y >> 16)) +
                      bf2f((unsigned short)(v3.y >> 16));
            }
            for (; j < m; j += 4) {                   // tail (proven R7 form)
                const int  e     = j + g;
                const bool valid = e < m;
                const int  s     = __shfl(sid, valid ? e : 0);
                const uint2 v = *(const uint2*)(xbf + (size_t)s * C + r * 4);
                if (valid) {
                    a0 += bf2f((unsigned short)(v.x & 0xffff));
                    a1 += bf2f((unsigned short)(v.x >> 16));
                    a2 += bf2f((unsigned short)(v.y & 0xffff));
                    a3 += bf2f((unsigned short)(v.y >> 16));
                }
            }
        }
        #pragma unroll
        for (int off = 16; off <= 32; off <<= 1) {    // cross-group reduce
            a0 += __shfl_xor(a0, off);
            a1 += __shfl_xor(a1, off);
            a2 += __shfl_xor(a2, off);
            a3 += __shfl_xor(a3, off);
        }
        if (g == 0) {
            const float inv = 1.0f / fmaxf((float)(end - beg), 1.0f);
            uint2 pv;
            pv.x = (unsigned)f2bf(a0 * inv) | ((unsigned)f2bf(a1 * inv) << 16);
            pv.y = (unsigned)f2bf(a2 * inv) | ((unsigned)f2bf(a3 * inv) << 16);
            *(uint2*)&aggs[w * 4 + i][r * 4] = pv;
        }
    }
    __syncthreads();

    // ---- phase 2: MFMA epilogue (wave w = channel tile w; R8-proven) ----
    const int q = lane >> 4;

    const bf16x8 bw0 = *(const bf16x8*)&wpack[(0*8 + 0*4 + w) * 64 + lane];
    const bf16x8 bw1 = *(const bf16x8*)&wpack[(0*8 + 1*4 + w) * 64 + lane];
    const bf16x8 br0 = *(const bf16x8*)&wpack[(1*8 + 0*4 + w) * 64 + lane];
    const bf16x8 br1 = *(const bf16x8*)&wpack[(1*8 + 1*4 + w) * 64 + lane];
    const float  bb  = bias[w * 16 + r];

    const unsigned short* rx = xbf + (size_t)(tileBase + r) * C;
    const bf16x8 a0 = *(const bf16x8*)&aggs[r][q * 8];
    const bf16x8 a1 = *(const bf16x8*)&aggs[r][32 + q * 8];
    const bf16x8 a2 = *(const bf16x8*)(rx + q * 8);
    const bf16x8 a3 = *(const bf16x8*)(rx + 32 + q * 8);

    f32x4 acc4 = {0.f, 0.f, 0.f, 0.f};
    acc4 = __builtin_amdgcn_mfma_f32_16x16x32_bf16(a0, bw0, acc4, 0, 0, 0);
    acc4 = __builtin_amdgcn_mfma_f32_16x16x32_bf16(a1, bw1, acc4, 0, 0, 0);
    acc4 = __builtin_amdgcn_mfma_f32_16x16x32_bf16(a2, br0, acc4, 0, 0, 0);
    acc4 = __builtin_amdgcn_mfma_f32_16x16x32_bf16(a3, br1, acc4, 0, 0, 0);

    #pragma unroll
    for (int i = 0; i < 4; ++i) {
        const int node = tileBase + q * 4 + i;
        out[(size_t)node * C + w * 16 + r] = fmaxf(acc4[i] + bb, 0.f);
    }
}

// ---------------------------------------------------------------------------
// Launch (R8-proven 4-dispatch pipeline, rebalanced grids). ws layout:
//   xbf          : ushort[3,200,000]   6.4 MB
//   wpack        : uint4[1024]         16 KB
//   bucketCursor : int[256]            (zeroed by kernel 0)
//   rowptr       : int[50,008]
//   ebuf         : int[800,000]        3.2 MB
//   bucketbuf    : int[196*6144]       4.8 MB     total ~14.7 MB
// ---------------------------------------------------------------------------
extern "C" void kernel_launch(void* const* d_in, const int* in_sizes, int n_in,
                              void* d_out, int out_size, void* d_ws, size_t ws_size,
                              hipStream_t stream)
{
    const float* x    = (const float*)d_in[0];
    const int*   ei   = (const int*)d_in[1];
    // d_in[2] = edge_attr: drops out for kernel_size=1 SplineConv
    const float* W    = (const float*)d_in[3];
    const float* R    = (const float*)d_in[4];
    const float* bias = (const float*)d_in[5];

    char* wsb = (char*)d_ws;
    unsigned short* xbf = (unsigned short*)wsb;
    size_t off = (size_t)N_NODES * C * sizeof(unsigned short);
    uint4* wpack        = (uint4*)(wsb + off);  off += 1024 * sizeof(uint4);
    int*   bucketCursor = (int*)(wsb + off);    off += 256 * sizeof(int);
    int*   rowptr       = (int*)(wsb + off);    off += ((N_NODES + 8) & ~3) * sizeof(int);
    int*   ebuf         = (int*)(wsb + off);    off += (size_t)N_EDGES * sizeof(int);
    int*   bucketbuf    = (int*)(wsb + off);
    float* out          = (float*)d_out;

    zero_cursor   <<<1, 256, 0, stream>>>(bucketCursor);
    prep_bin      <<<PB_BLOCKS, 256, 0, stream>>>(x, W, R, ei, xbf, wpack,
                                                  bucketCursor, bucketbuf);
    csr_place_scan<<<NBUCK, 512, 0, stream>>>(bucketCursor, bucketbuf, rowptr, ebuf);
    agg_mfma      <<<NAGG, 256, 0, stream>>>(rowptr, ebuf, xbf, wpack, bias, out);
}

// Round 15
// 58.976 us; speedup vs baseline: 1.5420x; 1.0164x over previous
//
#include <hip/hip_runtime.h>

#define N_NODES 50000
#define N_EDGES 800000
#define C 64                          // channels (C_IN == C_HID == 64)
// edge binning
#define BUCKET_NODES 256
#define NBUCK 196                     // ceil(50000/256)
#define BUCKET_CAP 6144               // mean 4082, +32 sigma (proven on this graph)
#define BIN_CHUNK 4096
#define NBIN_BLOCKS 196               // 196*4096 >= 800000
#define PREP_XBLOCKS 315
#define PB_BLOCKS (1 + PREP_XBLOCKS + NBIN_BLOCKS)           // 512 = 2 blocks/CU
#define BIN0 (1 + PREP_XBLOCKS)       // first bin block
// fused aggregate+mfma
#define AGG_NODES 16
#define NAGG (N_NODES / AGG_NODES)    // 3125 exactly (no tail)
#define LDSTR 72                      // LDS row stride in shorts (144 B, 16B-aligned rows)

typedef __attribute__((ext_vector_type(8))) short bf16x8;
typedef __attribute__((ext_vector_type(4))) float f32x4;

__device__ inline unsigned short f2bf(float f) {          // round-to-nearest-even
    union { float f; unsigned u; } v; v.f = f;
    unsigned r = v.u + 0x7FFF + ((v.u >> 16) & 1);
    return (unsigned short)(r >> 16);
}
__device__ inline float bf2f(unsigned short h) {
    union { unsigned u; float f; } v; v.u = (unsigned)h << 16;
    return v.f;
}

// ---------------------------------------------------------------------------
// Kernel 0: zero the 256-int bucket cursor (cheap dispatch, graph-friendly).
// ---------------------------------------------------------------------------
__global__ __launch_bounds__(256) void zero_cursor(int* __restrict__ c)
{
    c[threadIdx.x] = 0;
}

// ---------------------------------------------------------------------------
// Kernel 1 (fused, role-split by blockIdx) — R14-proven, one delta:
//   x-convert role ALSO writes xf8 (OCP fp8-e4m3, 3.2 MB) for the gather.
//   3.2 MB < 4 MB per-XCD L2 -> random gathers become L2-hits; bytes halve.
//   block 0            : pack W,root into bf16 MFMA B-fragments
//   blocks 1..315      : convert x -> bf16 (xbf) + fp8 (xf8)
//   blocks 316..511    : bin edges by dst>>8 (entry = (src<<8)|(dst&255))
// ---------------------------------------------------------------------------
__global__ __launch_bounds__(256) void prep_bin(
    const float* __restrict__ x,
    const float* __restrict__ W,
    const float* __restrict__ R,
    const int*   __restrict__ ei,
    unsigned short* __restrict__ xbf,
    unsigned* __restrict__ xf8w,          // 4 fp8 channels per word
    uint4* __restrict__ wpack,
    int* __restrict__ bucketCursor,
    int* __restrict__ bucketbuf)
{
    const int bid = blockIdx.x;

    if (bid == 0) {
        // ---- weight-pack role ----
        for (int s = threadIdx.x; s < 1024; s += 256) {
            const int f    = s >> 6;
            const int lane = s & 63;
            const int mat  = f >> 3, ks = (f >> 2) & 1, ct = f & 3;
            const float* src = mat ? R : W;
            const int kbase = ks * 32 + (lane >> 4) * 8;
            const int col   = ct * 16 + (lane & 15);
            unsigned wd[4];
            #pragma unroll
            for (int jj = 0; jj < 4; ++jj) {
                const unsigned lo16 = f2bf(src[(kbase + 2*jj    ) * C + col]);
                const unsigned hi16 = f2bf(src[(kbase + 2*jj + 1) * C + col]);
                wd[jj] = lo16 | (hi16 << 16);
            }
            uint4 o; o.x = wd[0]; o.y = wd[1]; o.z = wd[2]; o.w = wd[3];
            wpack[s] = o;
        }
        return;
    }

    if (bid < BIN0) {
        // ---- x-convert role (315 blocks): bf16 + fp8 ----
        const int nthreads = PREP_XBLOCKS * 256;
        const int total4 = (N_NODES * C) / 4;             // 800000 float4
        for (int i = (bid - 1) * 256 + threadIdx.x; i < total4; i += nthreads) {
            const float4 v = ((const float4*)x)[i];
            ushort4 o;
            o.x = f2bf(v.x); o.y = f2bf(v.y); o.z = f2bf(v.z); o.w = f2bf(v.w);
            ((ushort4*)xbf)[i] = o;
            int w8 = __builtin_amdgcn_cvt_pk_fp8_f32(v.x, v.y, 0, false);
            w8     = __builtin_amdgcn_cvt_pk_fp8_f32(v.z, v.w, w8, true);
            xf8w[i] = (unsigned)w8;
        }
        return;
    }

    // ---- edge-bin role (196 blocks; dst staged in LDS) ----
    __shared__ int sdst[BIN_CHUNK];                       // 16 KB
    __shared__ int cnt[NBUCK], cnt2[NBUCK], gb[NBUCK];
    for (int i = threadIdx.x; i < NBUCK; i += 256) { cnt[i] = 0; cnt2[i] = 0; }
    __syncthreads();

    const int bb = bid - BIN0;
    const int e0 = bb * BIN_CHUNK;
    const int e1 = min(e0 + BIN_CHUNK, N_EDGES);
    const int ne = e1 - e0;

    for (int k = threadIdx.x; k < ne; k += 256) {
        const int d = ei[N_EDGES + e0 + k];
        sdst[k] = d;
        atomicAdd(&cnt[((unsigned)d) >> 8], 1);
    }
    __syncthreads();

    for (int i = threadIdx.x; i < NBUCK; i += 256)
        gb[i] = atomicAdd(&bucketCursor[i], cnt[i]);
    __syncthreads();

    for (int k = threadIdx.x; k < ne; k += 256) {
        const int src = ei[e0 + k];
        const int dst = sdst[k];
        const int bkt = ((unsigned)dst) >> 8;
        const int off = gb[bkt] + atomicAdd(&cnt2[bkt], 1);
        bucketbuf[bkt * BUCKET_CAP + off] = (src << 8) | (dst & 255);
    }
}

// ---------------------------------------------------------------------------
// Kernel 2: per-bucket {stage entries, LDS degree-hist, block scan, rowptr
// write, CSR placement} — R14-proven (512 threads, 8 waves).
// ---------------------------------------------------------------------------
__global__ __launch_bounds__(512) void csr_place_scan(
    const int* __restrict__ bucketCursor,
    const int* __restrict__ bucketbuf,
    int* __restrict__ rowptr,
    int* __restrict__ ebuf)
{
    __shared__ int entries[BUCKET_CAP];                   // 24 KB
    __shared__ int lcur[BUCKET_NODES];
    __shared__ int wsum[4];
    __shared__ int boffS;

    const int b    = blockIdx.x;
    const int tid  = threadIdx.x;
    const int lane = tid & 63, w = tid >> 6;
    const int lo   = b * BUCKET_NODES;
    const int nn   = min(BUCKET_NODES, N_NODES - lo);
    const int cnt  = bucketCursor[b];

    if (w == 0) {                                         // bucket-offset scan
        const int base = lane * 4;
        int s0 = (base+0 < NBUCK) ? bucketCursor[base+0] : 0;
        int s1 = (base+1 < NBUCK) ? bucketCursor[base+1] : 0;
        int s2 = (base+2 < NBUCK) ? bucketCursor[base+2] : 0;
        int s3 = (base+3 < NBUCK) ? bucketCursor[base+3] : 0;
        const int tot = s0 + s1 + s2 + s3;
        int incl = tot;
        #pragma unroll
        for (int off = 1; off < 64; off <<= 1) {
            const int t = __shfl_up(incl, off);
            if (lane >= off) incl += t;
        }
        if (lane == (b >> 2)) {
            int v = incl - tot;
            if ((b & 3) > 0) v += s0;
            if ((b & 3) > 1) v += s1;
            if ((b & 3) > 2) v += s2;
            boffS = v;
        }
    }

    if (tid < BUCKET_NODES) lcur[tid] = 0;
    for (int k = tid; k < cnt; k += 512) entries[k] = bucketbuf[b * BUCKET_CAP + k];
    __syncthreads();

    for (int k = tid; k < cnt; k += 512)
        atomicAdd(&lcur[entries[k] & 255], 1);            // LDS degree hist
    __syncthreads();

    int v = 0, incl = 0;
    if (tid < BUCKET_NODES) {                             // block exclusive scan
        v = (tid < nn) ? lcur[tid] : 0;
        incl = v;
        #pragma unroll
        for (int off = 1; off < 64; off <<= 1) {
            const int t = __shfl_up(incl, off);
            if (lane >= off) incl += t;
        }
        if (lane == 63) wsum[w] = incl;
    }
    __syncthreads();
    int excl = 0;
    if (tid < BUCKET_NODES) {
        int woff = boffS;
        for (int k2 = 0; k2 < 4; ++k2) if (k2 < w) woff += wsum[k2];
        excl = woff + incl - v;
    }
    __syncthreads();                                      // all v-reads done
    if (tid < nn) {
        rowptr[lo + tid] = excl;
        lcur[tid] = excl;
        if (lo + tid == N_NODES - 1) rowptr[N_NODES] = excl + v;
    }
    __syncthreads();

    for (int k = tid; k < cnt; k += 512) {                // placement
        const int p   = entries[k];
        const int pos = atomicAdd(&lcur[p & 255], 1);
        ebuf[pos] = p >> 8;
    }
}

// ---------------------------------------------------------------------------
// Kernel 3 (fused): aggregate x (mean over incoming edges) into an LDS tile,
// then MFMA epilogue: out = relu( aggx @ W + x @ root + bias ).
// R13/R14-proven structure; ONLY delta: gather reads fp8 rows (4 B/lane,
// 64 B/edge-row) from the L2-resident xf8, decoded with v_cvt_f32_fp8.
// ---------------------------------------------------------------------------
__global__ __launch_bounds__(256) void agg_mfma(
    const int* __restrict__ rowptr,
    const int* __restrict__ ebuf,
    const unsigned short* __restrict__ xbf,
    const unsigned* __restrict__ xf8w,
    const uint4*  __restrict__ wpack,
    const float*  __restrict__ bias,
    float* __restrict__ out)
{
    __shared__ unsigned short aggs[AGG_NODES][LDSTR];

    const int lane = threadIdx.x & 63;
    const int w    = threadIdx.x >> 6;
    const int tileBase = (int)blockIdx.x * AGG_NODES;

    const int r = lane & 15;      // channel-quad id: channels [4r, 4r+4)
    const int g = lane >> 4;      // edge-group id 0..3

    // ---- phase 1: aggregation (4 nodes per wave) ----
    #pragma unroll
    for (int i = 0; i < 4; ++i) {
        const int n   = tileBase + w * 4 + i;
        const int beg = rowptr[n];
        const int end = rowptr[n + 1];
        float a0 = 0.f, a1 = 0.f, a2 = 0.f, a3 = 0.f;
        for (int base = beg; base < end; base += 64) {
            const int m = min(64, end - base);
            const int sid = (base + lane < end) ? ebuf[base + lane] : 0;
            int j = 0;
            for (; j + 16 <= m; j += 16) {            // 4 gathers in flight
                const int s0 = __shfl(sid, j + g);
                const int s1 = __shfl(sid, j + 4  + g);
                const int s2 = __shfl(sid, j + 8  + g);
                const int s3 = __shfl(sid, j + 12 + g);
                const unsigned u0 = xf8w[(size_t)s0 * 16 + r];
                const unsigned u1 = xf8w[(size_t)s1 * 16 + r];
                const unsigned u2 = xf8w[(size_t)s2 * 16 + r];
                const unsigned u3 = xf8w[(size_t)s3 * 16 + r];
                a0 += __builtin_amdgcn_cvt_f32_fp8((int)u0, 0) +
                      __builtin_amdgcn_cvt_f32_fp8((int)u1, 0) +
                      __builtin_amdgcn_cvt_f32_fp8((int)u2, 0) +
                      __builtin_amdgcn_cvt_f32_fp8((int)u3, 0);
                a1 += __builtin_amdgcn_cvt_f32_fp8((int)u0, 1) +
                      __builtin_amdgcn_cvt_f32_fp8((int)u1, 1) +
                      __builtin_amdgcn_cvt_f32_fp8((int)u2, 1) +
                      __builtin_amdgcn_cvt_f32_fp8((int)u3, 1);
                a2 += __builtin_amdgcn_cvt_f32_fp8((int)u0, 2) +
                      __builtin_amdgcn_cvt_f32_fp8((int)u1, 2) +
                      __builtin_amdgcn_cvt_f32_fp8((int)u2, 2) +
                      __builtin_amdgcn_cvt_f32_fp8((int)u3, 2);
                a3 += __builtin_amdgcn_cvt_f32_fp8((int)u0, 3) +
                      __builtin_amdgcn_cvt_f32_fp8((int)u1, 3) +
                      __builtin_amdgcn_cvt_f32_fp8((int)u2, 3) +
                      __builtin_amdgcn_cvt_f32_fp8((int)u3, 3);
            }
            for (; j < m; j += 4) {                   // tail
                const int  e     = j + g;
                const bool valid = e < m;
                const int  s     = __shfl(sid, valid ? e : 0);
                const unsigned u = xf8w[(size_t)s * 16 + r];
                if (valid) {
                    a0 += __builtin_amdgcn_cvt_f32_fp8((int)u, 0);
                    a1 += __builtin_amdgcn_cvt_f32_fp8((int)u, 1);
                    a2 += __builtin_amdgcn_cvt_f32_fp8((int)u, 2);
                    a3 += __builtin_amdgcn_cvt_f32_fp8((int)u, 3);
                }
            }
        }
        #pragma unroll
        for (int off = 16; off <= 32; off <<= 1) {    // cross-group reduce
            a0 += __shfl_xor(a0, off);
            a1 += __shfl_xor(a1, off);
            a2 += __shfl_xor(a2, off);
            a3 += __shfl_xor(a3, off);
        }
        if (g == 0) {
            const float inv = 1.0f / fmaxf((float)(end - beg), 1.0f);
            uint2 pv;
            pv.x = (unsigned)f2bf(a0 * inv) | ((unsigned)f2bf(a1 * inv) << 16);
            pv.y = (unsigned)f2bf(a2 * inv) | ((unsigned)f2bf(a3 * inv) << 16);
            *(uint2*)&aggs[w * 4 + i][r * 4] = pv;
        }
    }
    __syncthreads();

    // ---- phase 2: MFMA epilogue (wave w = channel tile w; R8-proven) ----
    const int q = lane >> 4;

    const bf16x8 bw0 = *(const bf16x8*)&wpack[(0*8 + 0*4 + w) * 64 + lane];
    const bf16x8 bw1 = *(const bf16x8*)&wpack[(0*8 + 1*4 + w) * 64 + lane];
    const bf16x8 br0 = *(const bf16x8*)&wpack[(1*8 + 0*4 + w) * 64 + lane];
    const bf16x8 br1 = *(const bf16x8*)&wpack[(1*8 + 1*4 + w) * 64 + lane];
    const float  bb  = bias[w * 16 + r];

    const unsigned short* rx = xbf + (size_t)(tileBase + r) * C;
    const bf16x8 a0 = *(const bf16x8*)&aggs[r][q * 8];
    const bf16x8 a1 = *(const bf16x8*)&aggs[r][32 + q * 8];
    const bf16x8 a2 = *(const bf16x8*)(rx + q * 8);
    const bf16x8 a3 = *(const bf16x8*)(rx + 32 + q * 8);

    f32x4 acc4 = {0.f, 0.f, 0.f, 0.f};
    acc4 = __builtin_amdgcn_mfma_f32_16x16x32_bf16(a0, bw0, acc4, 0, 0, 0);
    acc4 = __builtin_amdgcn_mfma_f32_16x16x32_bf16(a1, bw1, acc4, 0, 0, 0);
    acc4 = __builtin_amdgcn_mfma_f32_16x16x32_bf16(a2, br0, acc4, 0, 0, 0);
    acc4 = __builtin_amdgcn_mfma_f32_16x16x32_bf16(a3, br1, acc4, 0, 0, 0);

    #pragma unroll
    for (int i = 0; i < 4; ++i) {
        const int node = tileBase + q * 4 + i;
        out[(size_t)node * C + w * 16 + r] = fmaxf(acc4[i] + bb, 0.f);
    }
}

// ---------------------------------------------------------------------------
// Launch (4-dispatch pipeline). ws layout (16B-aligned):
//   xbf          : ushort[3,200,000]   6.4 MB
//   xf8          : uint[800,000]       3.2 MB   (fp8 e4m3, 4 ch/word)
//   wpack        : uint4[1024]         16 KB
//   bucketCursor : int[256]            (zeroed by kernel 0)
//   rowptr       : int[50,008]
//   ebuf         : int[800,000]        3.2 MB
//   bucketbuf    : int[196*6144]       4.8 MB     total ~17.9 MB
// ---------------------------------------------------------------------------
extern "C" void kernel_launch(void* const* d_in, const int* in_sizes, int n_in,
                              void* d_out, int out_size, void* d_ws, size_t ws_size,
                              hipStream_t stream)
{
    const float* x    = (const float*)d_in[0];
    const int*   ei   = (const int*)d_in[1];
    // d_in[2] = edge_attr: drops out for kernel_size=1 SplineConv
    const float* W    = (const float*)d_in[3];
    const float* R    = (const float*)d_in[4];
    const float* bias = (const float*)d_in[5];

    char* wsb = (char*)d_ws;
    unsigned short* xbf = (unsigned short*)wsb;
    size_t off = (size_t)N_NODES * C * sizeof(unsigned short);
    unsigned* xf8w      = (unsigned*)(wsb + off); off += (size_t)N_NODES * 16 * sizeof(unsigned);
    uint4* wpack        = (uint4*)(wsb + off);  off += 1024 * sizeof(uint4);
    int*   bucketCursor = (int*)(wsb + off);    off += 256 * sizeof(int);
    int*   rowptr       = (int*)(wsb + off);    off += ((N_NODES + 8) & ~3) * sizeof(int);
    int*   ebuf         = (int*)(wsb + off);    off += (size_t)N_EDGES * sizeof(int);
    int*   bucketbuf    = (int*)(wsb + off);
    float* out          = (float*)d_out;

    zero_cursor   <<<1, 256, 0, stream>>>(bucketCursor);
    prep_bin      <<<PB_BLOCKS, 256, 0, stream>>>(x, W, R, ei, xbf, xf8w, wpack,
                                                  bucketCursor, bucketbuf);
    csr_place_scan<<<NBUCK, 512, 0, stream>>>(bucketCursor, bucketbuf, rowptr, ebuf);
    agg_mfma      <<<NAGG, 256, 0, stream>>>(rowptr, ebuf, xbf, xf8w, wpack, bias, out);
}